// Round 9
// baseline (922.128 us; speedup 1.0000x reference)
//
#include <hip/hip_runtime.h>

// Problem constants: N=8, T=256, H=8, KQ=128, V=32
#define N_ 8
#define T_ 256
#define H_ 8
#define KQ_ 128
#define V_ 32
#define QT_ 8   // q rows per attn block

// DIAGNOSTIC ROUND 2: proj-v2 and attn bodies repeated 8x (idempotent) to
// surface both in top-5 rocprof rows with counters. Remove next round.
#define REPEAT 8

typedef float f32x4 __attribute__((ext_vector_type(4)));

// ---------------------------------------------------------------------------
// Phase 1 v2 (unchanged from R8, now instrumented x8):
// grid: 2048 = proj(2) * n(8) * h(8) * tt(8 of 32 rows) * dg2(2 of 64 d)
// ---------------------------------------------------------------------------
__global__ __launch_bounds__(256) void proj_kernel(
    const float* __restrict__ query, const float* __restrict__ key,
    const float* __restrict__ Wq, const float* __restrict__ bq,
    const float* __restrict__ Wk, const float* __restrict__ bk,
    float* __restrict__ hqT, float* __restrict__ hkT)
{
  int b = blockIdx.x;
  int dg2 = b & 1;
  int tt  = (b >> 1) & 7;
  int h   = (b >> 4) & 7;
  int n   = (b >> 7) & 7;
  int proj = b >> 10;
  const float* src  = proj ? key : query;
  const float* W    = proj ? Wk  : Wq;
  const float* bias = proj ? bk  : bq;
  float* dst        = proj ? hkT : hqT;
  int t0 = tt * 32;

  __shared__ float qs[32 * 132];

#pragma unroll 1
  for (int it = 0; it < REPEAT; ++it) {
    asm volatile("" ::: "memory");
    {
      const float* srcb = src + ((size_t)n * T_ + t0) * KQ_;
      for (int i = threadIdx.x; i < 32 * 32; i += 256) {
        int r = i >> 5, c4 = i & 31;
        *(float4*)&qs[r * 132 + c4 * 4] = *(const float4*)&srcb[(size_t)r * KQ_ + c4 * 4];
      }
    }
    __syncthreads();

    int tl   = threadIdx.x & 31;
    int dsub = threadIdx.x >> 5;
    int dbase = dg2 * 64 + dsub * 8;
    float acc[8];
#pragma unroll
    for (int dd = 0; dd < 8; ++dd) acc[dd] = 0.f;
    const float* wbase = W + (size_t)(h * KQ_ + dbase) * KQ_;

    for (int j0 = 0; j0 < 128; j0 += 16) {
      float qv[16];
#pragma unroll
      for (int c4 = 0; c4 < 4; ++c4)
        *(float4*)&qv[c4 * 4] = *(const float4*)&qs[tl * 132 + j0 + c4 * 4];
#pragma unroll
      for (int dd = 0; dd < 8; ++dd) {
        const float* wrow = wbase + (size_t)dd * KQ_ + j0;
#pragma unroll
        for (int c4 = 0; c4 < 4; ++c4) {
          float4 w4 = *(const float4*)&wrow[c4 * 4];
          acc[dd] = fmaf(qv[c4*4+0], w4.x, acc[dd]);
          acc[dd] = fmaf(qv[c4*4+1], w4.y, acc[dd]);
          acc[dd] = fmaf(qv[c4*4+2], w4.z, acc[dd]);
          acc[dd] = fmaf(qv[c4*4+3], w4.w, acc[dd]);
        }
      }
    }
#pragma unroll
    for (int dd = 0; dd < 8; ++dd) {
      int d = dbase + dd;
      dst[(((size_t)n * H_ + h) * KQ_ + d) * T_ + t0 + tl] = acc[dd] + bias[h * KQ_ + d];
    }
    __syncthreads();
  }
}

// ---------------------------------------------------------------------------
// Phase 2a (unchanged from R8, now instrumented x8)
// grid: 2048 = n(8) * h(8) * qtile(32 of 8 q's), 256 threads
// ---------------------------------------------------------------------------
#define EPAD 9

__global__ __launch_bounds__(256) void attn_kernel(
    const float* __restrict__ hqT, const float* __restrict__ hkT,
    const int* __restrict__ mask, const float* __restrict__ value,
    float* __restrict__ e_ws, float* __restrict__ inv_ws,
    float* __restrict__ out_ws)
{
  const float SCALE = 0.08838834764831845f;   // 1/sqrt(128)
  int b = blockIdx.x;
  int q0 = (b & 31) * QT_;
  int h  = (b >> 5) & 7;
  int n  = b >> 8;
  int t  = threadIdx.x;
  int row0 = (n * H_ + h) * T_ + q0;

  __shared__ float hq_s[KQ_ * 8];
  __shared__ float e_s[T_ * EPAD];
  __shared__ float wred[4 * 8];
  __shared__ float red_s[8 * 8 * 32];
  __shared__ float red_o[8 * 8 * 32];

  const float* hqbase = hqT + ((size_t)n * H_ + h) * KQ_ * T_;
  const float* hkbase = hkT + ((size_t)n * H_ + h) * KQ_ * T_;

#pragma unroll 1
  for (int it = 0; it < REPEAT; ++it) {
    asm volatile("" ::: "memory");
    {
      int qq = t & 7, j0 = t >> 3;
#pragma unroll
      for (int rep = 0; rep < 4; ++rep) {
        int j = j0 + rep * 32;
        hq_s[j * 8 + qq] = hqbase[(size_t)j * T_ + q0 + qq];
      }
    }
    __syncthreads();

    float acc[8];
#pragma unroll
    for (int qq = 0; qq < 8; ++qq) acc[qq] = 0.f;
#pragma unroll 4
    for (int j = 0; j < KQ_; ++j) {
      float hk = hkbase[(size_t)j * T_ + t];
      float4 a0 = *(const float4*)&hq_s[j * 8];
      float4 a1 = *(const float4*)&hq_s[j * 8 + 4];
      acc[0] = fmaf(a0.x, hk, acc[0]);
      acc[1] = fmaf(a0.y, hk, acc[1]);
      acc[2] = fmaf(a0.z, hk, acc[2]);
      acc[3] = fmaf(a0.w, hk, acc[3]);
      acc[4] = fmaf(a1.x, hk, acc[4]);
      acc[5] = fmaf(a1.y, hk, acc[5]);
      acc[6] = fmaf(a1.z, hk, acc[6]);
      acc[7] = fmaf(a1.w, hk, acc[7]);
    }
#pragma unroll
    for (int qq = 0; qq < 8; ++qq) acc[qq] *= SCALE;

    float mloc[8];
#pragma unroll
    for (int qq = 0; qq < 8; ++qq) {
      float m = acc[qq];
      for (int off = 32; off >= 1; off >>= 1)
        m = fmaxf(m, __shfl_xor(m, off, 64));
      mloc[qq] = m;
    }
    if ((t & 63) == 0) {
      int w = t >> 6;
#pragma unroll
      for (int qq = 0; qq < 8; ++qq) wred[w * 8 + qq] = mloc[qq];
    }
    __syncthreads();
    {
      float ev[8];
#pragma unroll
      for (int qq = 0; qq < 8; ++qq) {
        float mx = fmaxf(fmaxf(wred[0*8+qq], wred[1*8+qq]),
                         fmaxf(wred[2*8+qq], wred[3*8+qq]));
        ev[qq] = __expf(acc[qq] - mx);
      }
      *(float4*)&e_s[t * EPAD]     = make_float4(ev[0], ev[1], ev[2], ev[3]);
      *(float4*)&e_s[t * EPAD + 4] = make_float4(ev[4], ev[5], ev[6], ev[7]);
#pragma unroll
      for (int qq = 0; qq < 8; ++qq)
        e_ws[(size_t)(row0 + qq) * T_ + t] = ev[qq];
    }
    __syncthreads();

    const int*   mrow = mask  + (size_t)n * T_ * V_;
    const float* vrow = value + (size_t)n * T_ * V_;
    int v = t & 31, kg = t >> 5;
    float s8[8], o8[8];
#pragma unroll
    for (int qq = 0; qq < 8; ++qq) { s8[qq] = 0.f; o8[qq] = 0.f; }
    for (int i = 0; i < 32; ++i) {
      int k = kg * 32 + i;
      float mf = (float)mrow[k * V_ + v];
      float vv = vrow[k * V_ + v];
      float4 e0 = *(const float4*)&e_s[k * EPAD];
      float4 e1 = *(const float4*)&e_s[k * EPAD + 4];
      float p;
      p = e0.x * mf; s8[0] += p; o8[0] = fmaf(p, vv, o8[0]);
      p = e0.y * mf; s8[1] += p; o8[1] = fmaf(p, vv, o8[1]);
      p = e0.z * mf; s8[2] += p; o8[2] = fmaf(p, vv, o8[2]);
      p = e0.w * mf; s8[3] += p; o8[3] = fmaf(p, vv, o8[3]);
      p = e1.x * mf; s8[4] += p; o8[4] = fmaf(p, vv, o8[4]);
      p = e1.y * mf; s8[5] += p; o8[5] = fmaf(p, vv, o8[5]);
      p = e1.z * mf; s8[6] += p; o8[6] = fmaf(p, vv, o8[6]);
      p = e1.w * mf; s8[7] += p; o8[7] = fmaf(p, vv, o8[7]);
    }
#pragma unroll
    for (int qq = 0; qq < 8; ++qq) {
      red_s[(kg * 8 + qq) * 32 + v] = s8[qq];
      red_o[(kg * 8 + qq) * 32 + v] = o8[qq];
    }
    __syncthreads();
    {
      int qq = t >> 5, v2 = t & 31;
      float s = 0.f, o = 0.f;
#pragma unroll
      for (int kg2 = 0; kg2 < 8; ++kg2) {
        s += red_s[(kg2 * 8 + qq) * 32 + v2];
        o += red_o[(kg2 * 8 + qq) * 32 + v2];
      }
      float inv = 1.0f / s;
      inv_ws[(size_t)(row0 + qq) * V_ + v2] = inv;
      out_ws[(((size_t)n * T_ + q0 + qq) * H_ + h) * V_ + v2] = o * inv;
    }
    __syncthreads();
  }
}

// ---------------------------------------------------------------------------
// Phase 2b: streaming p_attn writes. Measured ~76-86us ≈ write roofline. FINAL.
// ---------------------------------------------------------------------------
__global__ __launch_bounds__(256) void pwrite_kernel(
    const float* __restrict__ e_ws, const float* __restrict__ inv_ws,
    const int* __restrict__ mask, float* __restrict__ p_out)
{
  int b = blockIdx.x;
  int row0 = b * 4;
  int n = row0 >> 11;
  const int* mrow = mask + (size_t)n * T_ * V_;
  int t = threadIdx.x;
  int v0 = (t & 7) * 4;
  int kbase = t >> 3;

  float4 iv[4];
  const float* erow[4];
  f32x4* dst4[4];
#pragma unroll
  for (int qq = 0; qq < 4; ++qq) {
    int row = row0 + qq;
    iv[qq]   = *(const float4*)&inv_ws[(size_t)row * V_ + v0];
    erow[qq] = e_ws + (size_t)row * T_;
    dst4[qq] = (f32x4*)p_out + (size_t)row * 2048;
  }

#pragma unroll
  for (int rep = 0; rep < 8; ++rep) {
    int k = rep * 32 + kbase;
    const int4 m4 = *(const int4*)&mrow[k * V_ + v0];
    float fx = (float)m4.x, fy = (float)m4.y, fz = (float)m4.z, fw = (float)m4.w;
#pragma unroll
    for (int qq = 0; qq < 4; ++qq) {
      float e = erow[qq][k];
      f32x4 pv;
      pv.x = e * fx * iv[qq].x;
      pv.y = e * fy * iv[qq].y;
      pv.z = e * fz * iv[qq].z;
      pv.w = e * fw * iv[qq].w;
      __builtin_nontemporal_store(pv, &dst4[qq][rep * 256 + t]);
    }
  }
}

// ---------------------------------------------------------------------------
// Phase 3 v2 (unchanged from R8)
// ---------------------------------------------------------------------------
__global__ __launch_bounds__(256) void outproj_kernel(
    const float* __restrict__ out_ws, const float* __restrict__ Wo,
    const float* __restrict__ bo, float* __restrict__ out_rep)
{
  __shared__ float wot[256 * 33];
  __shared__ float rows_s[4 * 256];
  __shared__ float red[4 * 32];
  int r0 = blockIdx.x * 4;
  for (int i = threadIdx.x; i < 32 * 256; i += 256) {
    int o = i >> 8, c = i & 255;
    wot[c * 33 + o] = Wo[i];
  }
  for (int i = threadIdx.x; i < 4 * 256; i += 256)
    rows_s[i] = out_ws[(size_t)r0 * 256 + i];
  __syncthreads();
  int o  = threadIdx.x & 31;
  int rr = (threadIdx.x >> 5) & 3;
  int kh = threadIdx.x >> 7;
  int cb = kh * 128;
  float acc = 0.f;
#pragma unroll 4
  for (int c = 0; c < 128; ++c)
    acc = fmaf(rows_s[rr * 256 + cb + c], wot[(cb + c) * 33 + o], acc);
  if (kh == 1) red[rr * 32 + o] = acc;
  __syncthreads();
  if (kh == 0)
    out_rep[(size_t)(r0 + rr) * 32 + o] = acc + red[rr * 32 + o] + bo[o];
}

// ---------------------------------------------------------------------------
extern "C" void kernel_launch(void* const* d_in, const int* in_sizes, int n_in,
                              void* d_out, int out_size, void* d_ws, size_t ws_size,
                              hipStream_t stream) {
  const float* value = (const float*)d_in[0];
  const float* key   = (const float*)d_in[1];
  const float* query = (const float*)d_in[2];
  const int*   mask  = (const int*)d_in[3];
  const float* Wq = (const float*)d_in[4];
  const float* bq = (const float*)d_in[5];
  const float* Wk = (const float*)d_in[6];
  const float* bk = (const float*)d_in[7];
  const float* Wo = (const float*)d_in[8];
  const float* bo = (const float*)d_in[9];

  float* out_rep = (float*)d_out;
  float* p_out   = (float*)d_out + (size_t)N_ * T_ * V_;

  float* hqT    = (float*)d_ws;
  float* hkT    = hqT    + (size_t)N_ * H_ * KQ_ * T_;
  float* out_ws = hkT    + (size_t)N_ * H_ * KQ_ * T_;
  float* e_ws   = out_ws + (size_t)N_ * T_ * H_ * V_;
  float* inv_ws = e_ws   + (size_t)N_ * H_ * T_ * T_;

  hipLaunchKernelGGL(proj_kernel, dim3(2048), dim3(256), 0, stream,
                     query, key, Wq, bq, Wk, bk, hqT, hkT);
  hipLaunchKernelGGL(attn_kernel, dim3(2048), dim3(256), 0, stream,
                     hqT, hkT, mask, value, e_ws, inv_ws, out_ws);
  hipLaunchKernelGGL(pwrite_kernel, dim3(4096), dim3(256), 0, stream,
                     e_ws, inv_ws, mask, p_out);
  hipLaunchKernelGGL(outproj_kernel, dim3(512), dim3(256), 0, stream,
                     out_ws, Wo, bo, out_rep);
}

// Round 10
// 170.351 us; speedup vs baseline: 5.4131x; 5.4131x over previous
//
#include <hip/hip_runtime.h>

// Problem constants: N=8, T=256, H=8, KQ=128, V=32
#define N_ 8
#define T_ 256
#define H_ 8
#define KQ_ 128
#define V_ 32
#define QT_ 8   // q rows per attn block

typedef float f32x4 __attribute__((ext_vector_type(4)));

// ---------------------------------------------------------------------------
// Phase 1 v3: tiled-GEMM projections, written TRANSPOSED: dst[n][h][d][t]
// R9 evidence: v1=65us(occ 22%), v2=64us(occ 51%) -> occupancy-independent;
// both had 1 t-row/thread => 4 FMA per W-load, 33M+ VMEM instrs. v3 stages
// q(64x128,pad132) + W(64x128) tiles in LDS (16 coalesced VMEM instr/thread),
// thread computes 2t x 8d; W LDS-reads half-wave-uniform (broadcast).
// grid: 1024 = proj(2)*n(8)*h(8)*tq(4 of 64t)*dh(2 of 64d), 256 thr, 66.5KB LDS
// ---------------------------------------------------------------------------
__global__ __launch_bounds__(256) void proj_kernel(
    const float* __restrict__ query, const float* __restrict__ key,
    const float* __restrict__ Wq, const float* __restrict__ bq,
    const float* __restrict__ Wk, const float* __restrict__ bk,
    float* __restrict__ hqT, float* __restrict__ hkT)
{
  int b = blockIdx.x;
  int dh = b & 1;
  int tq = (b >> 1) & 3;
  int h  = (b >> 3) & 7;
  int n  = (b >> 6) & 7;
  int proj = b >> 9;
  const float* src  = proj ? key : query;
  const float* W    = proj ? Wk  : Wq;
  const float* bias = proj ? bk  : bq;
  float* dst        = proj ? hkT : hqT;
  int t0 = tq * 64;
  int d0 = dh * 64;

  __shared__ float qs[64 * 132];   // q tile [t][j], pad 132
  __shared__ float ws[64 * 128];   // W tile [d][j]

  {
    const float* qsrc = src + ((size_t)n * T_ + t0) * KQ_;
    const float* wsrc = W + (size_t)(h * KQ_ + d0) * KQ_;
    for (int i = threadIdx.x; i < 64 * 32; i += 256) {   // float4 units
      int r = i >> 5, c4 = (i & 31) * 4;
      *(float4*)&qs[r * 132 + c4] = *(const float4*)&qsrc[(size_t)r * KQ_ + c4];
      *(float4*)&ws[r * 128 + c4] = *(const float4*)&wsrc[(size_t)r * KQ_ + c4];
    }
  }
  __syncthreads();

  int tl   = threadIdx.x & 31;      // lane -> t (coalesced stores)
  int dsub = threadIdx.x >> 5;      // 8 d's per thread, uniform per half-wave
  float acc0[8], acc1[8];
#pragma unroll
  for (int dd = 0; dd < 8; ++dd) { acc0[dd] = 0.f; acc1[dd] = 0.f; }

#pragma unroll 4
  for (int j0 = 0; j0 < 128; j0 += 4) {
    float4 q0 = *(const float4*)&qs[tl * 132 + j0];
    float4 q1 = *(const float4*)&qs[(tl + 32) * 132 + j0];
#pragma unroll
    for (int dd = 0; dd < 8; ++dd) {
      float4 w4 = *(const float4*)&ws[(dsub * 8 + dd) * 128 + j0];  // broadcast
      acc0[dd] = fmaf(q0.x, w4.x, acc0[dd]);
      acc0[dd] = fmaf(q0.y, w4.y, acc0[dd]);
      acc0[dd] = fmaf(q0.z, w4.z, acc0[dd]);
      acc0[dd] = fmaf(q0.w, w4.w, acc0[dd]);
      acc1[dd] = fmaf(q1.x, w4.x, acc1[dd]);
      acc1[dd] = fmaf(q1.y, w4.y, acc1[dd]);
      acc1[dd] = fmaf(q1.z, w4.z, acc1[dd]);
      acc1[dd] = fmaf(q1.w, w4.w, acc1[dd]);
    }
  }

#pragma unroll
  for (int dd = 0; dd < 8; ++dd) {
    int d = d0 + dsub * 8 + dd;
    float bb = bias[h * KQ_ + d];
    size_t base = (((size_t)n * H_ + h) * KQ_ + d) * T_ + t0;
    dst[base + tl]      = acc0[dd] + bb;   // lanes tl consecutive: coalesced
    dst[base + tl + 32] = acc1[dd] + bb;
  }
}

// ---------------------------------------------------------------------------
// Phase 2a (frozen from R8): scores -> softmax e -> denominators -> out_ws
// Measured (R9 inference): ~38us. Next target after proj.
// grid: 2048 = n(8) * h(8) * qtile(32 of 8 q's), 256 threads
// ---------------------------------------------------------------------------
#define EPAD 9

__global__ __launch_bounds__(256) void attn_kernel(
    const float* __restrict__ hqT, const float* __restrict__ hkT,
    const int* __restrict__ mask, const float* __restrict__ value,
    float* __restrict__ e_ws, float* __restrict__ inv_ws,
    float* __restrict__ out_ws)
{
  const float SCALE = 0.08838834764831845f;   // 1/sqrt(128)
  int b = blockIdx.x;
  int q0 = (b & 31) * QT_;
  int h  = (b >> 5) & 7;
  int n  = b >> 8;
  int t  = threadIdx.x;
  int row0 = (n * H_ + h) * T_ + q0;

  __shared__ float hq_s[KQ_ * 8];
  __shared__ float e_s[T_ * EPAD];
  __shared__ float wred[4 * 8];
  __shared__ float red_s[8 * 8 * 32];
  __shared__ float red_o[8 * 8 * 32];

  const float* hqbase = hqT + ((size_t)n * H_ + h) * KQ_ * T_;
  const float* hkbase = hkT + ((size_t)n * H_ + h) * KQ_ * T_;

  {
    int qq = t & 7, j0 = t >> 3;
#pragma unroll
    for (int rep = 0; rep < 4; ++rep) {
      int j = j0 + rep * 32;
      hq_s[j * 8 + qq] = hqbase[(size_t)j * T_ + q0 + qq];
    }
  }
  __syncthreads();

  float acc[8];
#pragma unroll
  for (int qq = 0; qq < 8; ++qq) acc[qq] = 0.f;
#pragma unroll 4
  for (int j = 0; j < KQ_; ++j) {
    float hk = hkbase[(size_t)j * T_ + t];
    float4 a0 = *(const float4*)&hq_s[j * 8];
    float4 a1 = *(const float4*)&hq_s[j * 8 + 4];
    acc[0] = fmaf(a0.x, hk, acc[0]);
    acc[1] = fmaf(a0.y, hk, acc[1]);
    acc[2] = fmaf(a0.z, hk, acc[2]);
    acc[3] = fmaf(a0.w, hk, acc[3]);
    acc[4] = fmaf(a1.x, hk, acc[4]);
    acc[5] = fmaf(a1.y, hk, acc[5]);
    acc[6] = fmaf(a1.z, hk, acc[6]);
    acc[7] = fmaf(a1.w, hk, acc[7]);
  }
#pragma unroll
  for (int qq = 0; qq < 8; ++qq) acc[qq] *= SCALE;

  float mloc[8];
#pragma unroll
  for (int qq = 0; qq < 8; ++qq) {
    float m = acc[qq];
    for (int off = 32; off >= 1; off >>= 1)
      m = fmaxf(m, __shfl_xor(m, off, 64));
    mloc[qq] = m;
  }
  if ((t & 63) == 0) {
    int w = t >> 6;
#pragma unroll
    for (int qq = 0; qq < 8; ++qq) wred[w * 8 + qq] = mloc[qq];
  }
  __syncthreads();
  {
    float ev[8];
#pragma unroll
    for (int qq = 0; qq < 8; ++qq) {
      float mx = fmaxf(fmaxf(wred[0*8+qq], wred[1*8+qq]),
                       fmaxf(wred[2*8+qq], wred[3*8+qq]));
      ev[qq] = __expf(acc[qq] - mx);
    }
    *(float4*)&e_s[t * EPAD]     = make_float4(ev[0], ev[1], ev[2], ev[3]);
    *(float4*)&e_s[t * EPAD + 4] = make_float4(ev[4], ev[5], ev[6], ev[7]);
#pragma unroll
    for (int qq = 0; qq < 8; ++qq)
      e_ws[(size_t)(row0 + qq) * T_ + t] = ev[qq];
  }
  __syncthreads();

  const int*   mrow = mask  + (size_t)n * T_ * V_;
  const float* vrow = value + (size_t)n * T_ * V_;
  int v = t & 31, kg = t >> 5;
  float s8[8], o8[8];
#pragma unroll
  for (int qq = 0; qq < 8; ++qq) { s8[qq] = 0.f; o8[qq] = 0.f; }
  for (int i = 0; i < 32; ++i) {
    int k = kg * 32 + i;
    float mf = (float)mrow[k * V_ + v];
    float vv = vrow[k * V_ + v];
    float4 e0 = *(const float4*)&e_s[k * EPAD];
    float4 e1 = *(const float4*)&e_s[k * EPAD + 4];
    float p;
    p = e0.x * mf; s8[0] += p; o8[0] = fmaf(p, vv, o8[0]);
    p = e0.y * mf; s8[1] += p; o8[1] = fmaf(p, vv, o8[1]);
    p = e0.z * mf; s8[2] += p; o8[2] = fmaf(p, vv, o8[2]);
    p = e0.w * mf; s8[3] += p; o8[3] = fmaf(p, vv, o8[3]);
    p = e1.x * mf; s8[4] += p; o8[4] = fmaf(p, vv, o8[4]);
    p = e1.y * mf; s8[5] += p; o8[5] = fmaf(p, vv, o8[5]);
    p = e1.z * mf; s8[6] += p; o8[6] = fmaf(p, vv, o8[6]);
    p = e1.w * mf; s8[7] += p; o8[7] = fmaf(p, vv, o8[7]);
  }
#pragma unroll
  for (int qq = 0; qq < 8; ++qq) {
    red_s[(kg * 8 + qq) * 32 + v] = s8[qq];
    red_o[(kg * 8 + qq) * 32 + v] = o8[qq];
  }
  __syncthreads();
  {
    int qq = t >> 5, v2 = t & 31;
    float s = 0.f, o = 0.f;
#pragma unroll
    for (int kg2 = 0; kg2 < 8; ++kg2) {
      s += red_s[(kg2 * 8 + qq) * 32 + v2];
      o += red_o[(kg2 * 8 + qq) * 32 + v2];
    }
    float inv = 1.0f / s;
    inv_ws[(size_t)(row0 + qq) * V_ + v2] = inv;
    out_ws[(((size_t)n * T_ + q0 + qq) * H_ + h) * V_ + v2] = o * inv;
  }
}

// ---------------------------------------------------------------------------
// Phase 2b: streaming p_attn writes. Measured ~76us ≈ write roofline. FINAL.
// ---------------------------------------------------------------------------
__global__ __launch_bounds__(256) void pwrite_kernel(
    const float* __restrict__ e_ws, const float* __restrict__ inv_ws,
    const int* __restrict__ mask, float* __restrict__ p_out)
{
  int b = blockIdx.x;
  int row0 = b * 4;
  int n = row0 >> 11;
  const int* mrow = mask + (size_t)n * T_ * V_;
  int t = threadIdx.x;
  int v0 = (t & 7) * 4;
  int kbase = t >> 3;

  float4 iv[4];
  const float* erow[4];
  f32x4* dst4[4];
#pragma unroll
  for (int qq = 0; qq < 4; ++qq) {
    int row = row0 + qq;
    iv[qq]   = *(const float4*)&inv_ws[(size_t)row * V_ + v0];
    erow[qq] = e_ws + (size_t)row * T_;
    dst4[qq] = (f32x4*)p_out + (size_t)row * 2048;
  }

#pragma unroll
  for (int rep = 0; rep < 8; ++rep) {
    int k = rep * 32 + kbase;
    const int4 m4 = *(const int4*)&mrow[k * V_ + v0];
    float fx = (float)m4.x, fy = (float)m4.y, fz = (float)m4.z, fw = (float)m4.w;
#pragma unroll
    for (int qq = 0; qq < 4; ++qq) {
      float e = erow[qq][k];
      f32x4 pv;
      pv.x = e * fx * iv[qq].x;
      pv.y = e * fy * iv[qq].y;
      pv.z = e * fz * iv[qq].z;
      pv.w = e * fw * iv[qq].w;
      __builtin_nontemporal_store(pv, &dst4[qq][rep * 256 + t]);
    }
  }
}

// ---------------------------------------------------------------------------
// Phase 3 v2 (frozen from R8)
// ---------------------------------------------------------------------------
__global__ __launch_bounds__(256) void outproj_kernel(
    const float* __restrict__ out_ws, const float* __restrict__ Wo,
    const float* __restrict__ bo, float* __restrict__ out_rep)
{
  __shared__ float wot[256 * 33];
  __shared__ float rows_s[4 * 256];
  __shared__ float red[4 * 32];
  int r0 = blockIdx.x * 4;
  for (int i = threadIdx.x; i < 32 * 256; i += 256) {
    int o = i >> 8, c = i & 255;
    wot[c * 33 + o] = Wo[i];
  }
  for (int i = threadIdx.x; i < 4 * 256; i += 256)
    rows_s[i] = out_ws[(size_t)r0 * 256 + i];
  __syncthreads();
  int o  = threadIdx.x & 31;
  int rr = (threadIdx.x >> 5) & 3;
  int kh = threadIdx.x >> 7;
  int cb = kh * 128;
  float acc = 0.f;
#pragma unroll 4
  for (int c = 0; c < 128; ++c)
    acc = fmaf(rows_s[rr * 256 + cb + c], wot[(cb + c) * 33 + o], acc);
  if (kh == 1) red[rr * 32 + o] = acc;
  __syncthreads();
  if (kh == 0)
    out_rep[(size_t)(r0 + rr) * 32 + o] = acc + red[rr * 32 + o] + bo[o];
}

// ---------------------------------------------------------------------------
extern "C" void kernel_launch(void* const* d_in, const int* in_sizes, int n_in,
                              void* d_out, int out_size, void* d_ws, size_t ws_size,
                              hipStream_t stream) {
  const float* value = (const float*)d_in[0];
  const float* key   = (const float*)d_in[1];
  const float* query = (const float*)d_in[2];
  const int*   mask  = (const int*)d_in[3];
  const float* Wq = (const float*)d_in[4];
  const float* bq = (const float*)d_in[5];
  const float* Wk = (const float*)d_in[6];
  const float* bk = (const float*)d_in[7];
  const float* Wo = (const float*)d_in[8];
  const float* bo = (const float*)d_in[9];

  float* out_rep = (float*)d_out;
  float* p_out   = (float*)d_out + (size_t)N_ * T_ * V_;

  float* hqT    = (float*)d_ws;
  float* hkT    = hqT    + (size_t)N_ * H_ * KQ_ * T_;
  float* out_ws = hkT    + (size_t)N_ * H_ * KQ_ * T_;
  float* e_ws   = out_ws + (size_t)N_ * T_ * H_ * V_;
  float* inv_ws = e_ws   + (size_t)N_ * H_ * T_ * T_;

  hipLaunchKernelGGL(proj_kernel, dim3(1024), dim3(256), 0, stream,
                     query, key, Wq, bq, Wk, bk, hqT, hkT);
  hipLaunchKernelGGL(attn_kernel, dim3(2048), dim3(256), 0, stream,
                     hqT, hkT, mask, value, e_ws, inv_ws, out_ws);
  hipLaunchKernelGGL(pwrite_kernel, dim3(4096), dim3(256), 0, stream,
                     e_ws, inv_ws, mask, p_out);
  hipLaunchKernelGGL(outproj_kernel, dim3(512), dim3(256), 0, stream,
                     out_ws, Wo, bo, out_rep);
}